// Round 14
// baseline (56.871 us; speedup 1.0000x reference)
//
#include <hip/hip_runtime.h>
#include <hip/hip_bf16.h>

#define BSZ   4
#define LSEQ  1024
#define NH    12
#define DDIM  768
#define NEN   42
#define NM    96
#define NPAIR (NEN*NEN)   /* 1764 */
#define OFF   1

typedef short bf16x8 __attribute__((ext_vector_type(8)));
typedef float f32x4  __attribute__((ext_vector_type(4)));

__device__ __forceinline__ float bf2f(unsigned short u) {
    union { unsigned u; float f; } c; c.u = ((unsigned)u) << 16; return c.f;
}

typedef const __attribute__((address_space(1))) unsigned int glb_u32;
typedef __attribute__((address_space(3))) unsigned int lds_u32;
__device__ __forceinline__ void glds16(const void* g, void* l) {
    __builtin_amdgcn_global_load_lds((glb_u32*)g, (lds_u32*)l, 16, 0, 0);
}

// ---------------- workspace layout ----------------
// f32: e_emb | psum   then bf16: e_att   then fp8: ptil | seqT
#define NLC   2                                     /* l-chunks (LSEQ/LCHK) */
#define EMB_CNT  (BSZ*NEN*DDIM)
#define PSUM_CNT (BSZ*NLC*NPAIR)
#define EATT_CNT (BSZ*NEN*NH*LSEQ)
#define PTIL_BYTES ((size_t)BSZ*NPAIR*LSEQ)

// K1: att | seq transpose | ent_emb  (all input-only)
#define ATT_BLKS  (BSZ*NEN*NH)                      /* 2016 */
#define T_BLKS    ((LSEQ/32)*(DDIM/32)*BSZ)         /* 3072 */
#define EMB_BLKS  (BSZ*NEN*3)                       /* 504 */
#define K1_TOTAL  (ATT_BLKS + T_BLKS + EMB_BLKS)

// K2: pair tiles | gather
#define TEN   6
#define NTILE 7                                     /* 42/6 */
#define NTRIT (NTILE*(NTILE+1)/2)                   /* 28 */
#define LCHK  512
#define PAIR_BLKS (NTRIT*NLC*BSZ)                   /* 224 */
#define GATH_BLKS (BSZ*NPAIR/4)                     /* 1764 */
#define K2_TOTAL  (PAIR_BLKS + GATH_BLKS)

// K3: fmap fp8 GEMM only (XCD-swizzled)
#define BM 128
#define BN 64
#define BK 128
#define MT 14           /* ceil(1764/128) */
#define NT (DDIM/BN)    /* 12 */
#define FMAP_BLKS (MT*NT*BSZ)                       /* 672, %8==0 */

// ================= kernel 1: att | seq2fp8T | ent_emb ========================
__global__ __launch_bounds__(256) void prep_kernel(
        const float* __restrict__ seq,
        const float* __restrict__ att,
        const int* __restrict__ mpos,
        const int* __restrict__ ment,
        __hip_bfloat16* __restrict__ e_att,
        unsigned char* __restrict__ seqT,
        float* __restrict__ e_emb) {
    __shared__ __align__(16) char smraw[4352];
    const int bid = blockIdx.x;
    const int t = threadIdx.x;

    if (bid < ATT_BLKS) {
        // ---------- ent_att: segment-mean of attention rows -> bf16 ----------
        int id = bid;
        int h = id % NH;
        int e = (id / NH) % NEN;
        int b = id / (NH * NEN);
        int* sp   = (int*)smraw;
        int* se   = sp + NM;
        int* list = se + NM;
        int* pcnt = list + NM;
        if (t < NM) { sp[t] = mpos[b*NM + t] + OFF; se[t] = ment[b*NM + t]; }
        __syncthreads();
        if (t == 0) {                        // deterministic compaction
            int c = 0;
            for (int m = 0; m < NM; ++m) if (se[m] == e) list[c++] = sp[m];
            pcnt[0] = c;
        }
        __syncthreads();
        int cnt = pcnt[0];
        const float* ab = att + ((size_t)(b*NH + h)) * LSEQ * LSEQ;
        float4 acc = {0.f, 0.f, 0.f, 0.f};
        for (int m = 0; m < cnt; ++m) {
            float4 v = ((const float4*)(ab + (size_t)list[m]*LSEQ))[t];
            acc.x += v.x; acc.y += v.y; acc.z += v.z; acc.w += v.w;
        }
        float inv = cnt ? 1.f / (float)cnt : 0.f;
        union { ushort4 u4; __hip_bfloat16 hh[4]; } pk;
        pk.hh[0] = __float2bfloat16(acc.x * inv);
        pk.hh[1] = __float2bfloat16(acc.y * inv);
        pk.hh[2] = __float2bfloat16(acc.z * inv);
        pk.hh[3] = __float2bfloat16(acc.w * inv);
        ((ushort4*)(e_att + ((size_t)(b*NEN + e)*NH + h)*LSEQ))[t] = pk.u4;
    } else if (bid < ATT_BLKS + T_BLKS) {
        // ---------- seq2fp8T: seq f32 [L][D] -> seqT fp8 [D][L] --------------
        int id = bid - ATT_BLKS;
        int l0 = (id % (LSEQ/32)) * 32;
        int d0 = ((id / (LSEQ/32)) % (DDIM/32)) * 32;
        int b  = id / ((LSEQ/32) * (DDIM/32));
        float (*tile)[33] = (float(*)[33])smraw;
        int l = t >> 3, dq = (t & 7) * 4;
        float4 v = *(const float4*)(seq + ((size_t)b*LSEQ + l0 + l)*DDIM + d0 + dq);
        tile[l][dq+0] = v.x; tile[l][dq+1] = v.y;
        tile[l][dq+2] = v.z; tile[l][dq+3] = v.w;
        __syncthreads();
        int d = t >> 3, lq = (t & 7) * 4;
        int w = __builtin_amdgcn_cvt_pk_fp8_f32(tile[lq+0][d], tile[lq+1][d], 0, false);
        w     = __builtin_amdgcn_cvt_pk_fp8_f32(tile[lq+2][d], tile[lq+3][d], w, true);
        *(int*)(seqT + ((size_t)b*DDIM + d0 + d)*LSEQ + l0 + lq) = w;
    } else {
        // ---------- ent_emb: segment logsumexp, one 256-d chunk per block ----
        int id = bid - ATT_BLKS - T_BLKS;
        int chunk = id % 3;
        int e = (id / 3) % NEN;
        int b = id / (3 * NEN);
        int* sp   = (int*)smraw;
        int* se   = sp + NM;
        int* list = se + NM;
        int* pcnt = list + NM;
        if (t < NM) { sp[t] = mpos[b*NM + t] + OFF; se[t] = ment[b*NM + t]; }
        __syncthreads();
        if (t == 0) {
            int c = 0;
            for (int m = 0; m < NM; ++m) if (se[m] == e) list[c++] = sp[m];
            pcnt[0] = c;
        }
        __syncthreads();
        int cnt = pcnt[0];
        int d = chunk * 256 + t;
        const float* sq = seq + (size_t)b * LSEQ * DDIM + d;
        float mx = -1e30f;
        for (int m = 0; m < cnt; ++m) mx = fmaxf(mx, sq[(size_t)list[m] * DDIM]);
        float out = 0.f;
        if (cnt) {
            float s = 0.f;
            for (int m = 0; m < cnt; ++m) s += expf(sq[(size_t)list[m] * DDIM] - mx);
            out = logf(fmaxf(s, 1e-30f)) + mx;
        }
        e_emb[((size_t)b*NEN + e)*DDIM + d] = out;
    }
}

// ================= kernel 2: pair tiles (+psum, fp8 out) | gather ============
__global__ __launch_bounds__(256) void mid_kernel(
        const __hip_bfloat16* __restrict__ e_att,
        const float* __restrict__ e_emb,
        const int* __restrict__ hts,
        unsigned char* __restrict__ ptil,
        float* __restrict__ psum,
        float* __restrict__ out_h,
        float* __restrict__ out_t) {
    __shared__ __align__(16) char smraw[640];
    const int bid = blockIdx.x;
    const int t = threadIdx.x;

    if (bid < PAIR_BLKS) {
        // ---------- pair: 6x6 entity tile x 512-l chunk (2 l/thread) ---------
        int tri = bid % NTRIT;
        int lc  = (bid / NTRIT) % NLC;
        int b   = bid / (NTRIT * NLC);
        int ta = 0, rem = tri;
        while (rem >= NTILE - ta) { rem -= NTILE - ta; ++ta; }
        int tb = ta + rem;
        int l = lc * LCHK + t * 2;

        const __hip_bfloat16* ebase = e_att + (size_t)b*NEN*NH*LSEQ + l;
        float sx[TEN][TEN], sy[TEN][TEN];
        #pragma unroll
        for (int i = 0; i < TEN; ++i)
            #pragma unroll
            for (int j = 0; j < TEN; ++j) { sx[i][j] = 0.f; sy[i][j] = 0.f; }

        #pragma unroll 4
        for (int h = 0; h < NH; ++h) {
            float xax[TEN], xay[TEN], xbx[TEN], xby[TEN];
            #pragma unroll
            for (int e = 0; e < TEN; ++e) {
                ushort2 u = *(const ushort2*)(ebase + ((size_t)(ta*TEN+e)*NH + h)*LSEQ);
                xax[e] = bf2f(u.x); xay[e] = bf2f(u.y);
            }
            #pragma unroll
            for (int e = 0; e < TEN; ++e) {
                ushort2 u = *(const ushort2*)(ebase + ((size_t)(tb*TEN+e)*NH + h)*LSEQ);
                xbx[e] = bf2f(u.x); xby[e] = bf2f(u.y);
            }
            #pragma unroll
            for (int i = 0; i < TEN; ++i)
                #pragma unroll
                for (int j = 0; j < TEN; ++j) {
                    sx[i][j] += xax[i] * xbx[j];
                    sy[i][j] += xay[i] * xby[j];
                }
        }

        unsigned char* pbase = ptil + (size_t)b*NPAIR*LSEQ + l;
        #pragma unroll
        for (int i = 0; i < TEN; ++i) {
            #pragma unroll
            for (int j = 0; j < TEN; ++j) {
                int w = __builtin_amdgcn_cvt_pk_fp8_f32(sx[i][j], sy[i][j], 0, false);
                unsigned short q = (unsigned short)(w & 0xFFFF);
                int pa = ta*TEN + i, pb = tb*TEN + j;
                *(unsigned short*)(pbase + (size_t)(pa*NEN + pb)*LSEQ) = q;
                if (ta != tb)
                    *(unsigned short*)(pbase + (size_t)(pb*NEN + pa)*LSEQ) = q;
            }
        }

        // ---- deterministic partial row sums: wave shfl reduce + LDS combine
        int lane = t & 63, w = t >> 6;
        float (*redp)[TEN*TEN] = (float(*)[TEN*TEN])smraw;  // [4][36]
        float keep = 0.f;
        #pragma unroll
        for (int i = 0; i < TEN; ++i) {
            #pragma unroll
            for (int j = 0; j < TEN; ++j) {
                float v = sx[i][j] + sy[i][j];
                v += __shfl_xor(v,  1, 64);
                v += __shfl_xor(v,  2, 64);
                v += __shfl_xor(v,  4, 64);
                v += __shfl_xor(v,  8, 64);
                v += __shfl_xor(v, 16, 64);
                v += __shfl_xor(v, 32, 64);
                if (lane == i*TEN + j) keep = v;
            }
        }
        if (lane < TEN*TEN) redp[w][lane] = keep;
        __syncthreads();
        if (t < TEN*TEN) {
            float v = redp[0][t] + redp[1][t] + redp[2][t] + redp[3][t];
            int i = t / TEN, j = t % TEN;
            int pa = ta*TEN + i, pb = tb*TEN + j;
            float* ps = psum + ((size_t)(b*NLC + lc))*NPAIR;
            ps[pa*NEN + pb] = v;
            if (ta != tb) ps[pb*NEN + pa] = v;
        }
    } else {
        // ---------- gather hss / tss: 4 pairs per block ----------------------
        int id4  = bid - PAIR_BLKS;
        int grp  = t >> 6;
        int lane = t & 63;
        int id   = id4 * 4 + grp;                // b*NPAIR + p
        int b    = id / NPAIR;
        int hi = hts[id*2 + 0];
        int ti = hts[id*2 + 1];
        const float4* eh = (const float4*)(e_emb + ((size_t)(b*NEN + hi))*DDIM);
        const float4* et = (const float4*)(e_emb + ((size_t)(b*NEN + ti))*DDIM);
        float4* oh = (float4*)(out_h + (size_t)id*DDIM);
        float4* ot = (float4*)(out_t + (size_t)id*DDIM);
        #pragma unroll
        for (int i = 0; i < 3; ++i) {            // 192 float4 per row
            oh[lane + 64*i] = eh[lane + 64*i];
            ot[lane + 64*i] = et[lane + 64*i];
        }
    }
}

// ================= kernel 3: fp8 fmap GEMM (BK=128, dbuf, XCD-swz) ===========
// LDS rows are 128 B (fp8). Swizzle: 16B slot ^= (row&7)  (glds 16B-aligned)
__global__ __launch_bounds__(256) void gemm_kernel(
        const unsigned char* __restrict__ ptil,
        const unsigned char* __restrict__ seqT,
        const float* __restrict__ psum,
        float* __restrict__ fmap) {
    __shared__ unsigned char As[2][BM*BK];      // 2 x 16 KB, swizzled linear
    __shared__ unsigned char Bs[2][BN*BK];      // 2 x  8 KB
    const int bid = blockIdx.x;
    const int t = threadIdx.x;

    int tile = (bid & 7) * (FMAP_BLKS/8) + (bid >> 3);
    const int lane = t & 63;
    const int wid  = t >> 6;
    const int wr   = wid >> 1;      // 0..1 : 64-row half
    const int wc   = wid & 1;       // 0..1 : 32-col half
    const int bx = tile % MT, by = (tile / MT) % NT, b = tile / (MT*NT);
    const int r0 = bx * BM, c0 = by * BN;

    const unsigned char* Ab  = ptil + (size_t)b * NPAIR * LSEQ;
    const unsigned char* Btb = seqT + (size_t)b * DDIM * LSEQ;
    unsigned char* AsB = (unsigned char*)As;
    unsigned char* BsB = (unsigned char*)Bs;

    const f32x4 zero = {0.f, 0.f, 0.f, 0.f};
    f32x4 acc[4][2];
    #pragma unroll
    for (int m = 0; m < 4; ++m)
        #pragma unroll
        for (int n = 0; n < 2; ++n) acc[m][n] = zero;

    const int fr = lane & 15, kg = lane >> 4;

#define STAGE(buf, k0)                                                        \
    {                                                                         \
        _Pragma("unroll")                                                     \
        for (int i = 0; i < 4; ++i) {                                         \
            int L = t*16 + i*4096;                                            \
            int r = L >> 7, beta = L & 127;                                   \
            glds16(Ab + (size_t)(r0 + r)*LSEQ + (k0)                          \
                      + (beta ^ ((r & 7) << 4)),                              \
                   AsB + (buf)*16384 + L);                                    \
        }                                                                     \
        _Pragma("unroll")                                                     \
        for (int i = 0; i < 2; ++i) {                                         \
            int L = t*16 + i*4096;                                            \
            int c = L >> 7, beta = L & 127;                                   \
            glds16(Btb + (size_t)(c0 + c)*LSEQ + (k0)                         \
                      + (beta ^ ((c & 7) << 4)),                              \
                   BsB + (buf)*8192 + L);                                     \
        }                                                                     \
    }

    STAGE(0, 0);
    __syncthreads();

    int cur = 0;
    for (int ki = 0; ki < LSEQ/BK; ++ki) {
        if (ki + 1 < LSEQ/BK) STAGE(cur ^ 1, (ki + 1) * BK);

        const unsigned char* Ac = AsB + cur*16384;
        const unsigned char* Bc = BsB + cur*8192;

        #pragma unroll
        for (int ks = 0; ks < 4; ++ks) {
            long af[4], bfv[2];
            #pragma unroll
            for (int m = 0; m < 4; ++m) {
                int R = wr*64 + m*16 + fr;
                int e0 = (ks*32 + kg*8) ^ ((R & 7) << 4);
                af[m] = *(const long*)(Ac + R*128 + e0);
            }
            #pragma unroll
            for (int n = 0; n < 2; ++n) {
                int C = wc*32 + n*16 + fr;
                int e0 = (ks*32 + kg*8) ^ ((C & 7) << 4);
                bfv[n] = *(const long*)(Bc + C*128 + e0);
            }
            #pragma unroll
            for (int m = 0; m < 4; ++m)
                #pragma unroll
                for (int n = 0; n < 2; ++n)
                    acc[m][n] = __builtin_amdgcn_mfma_f32_16x16x32_fp8_fp8(
                                    af[m], bfv[n], acc[m][n], 0, 0, 0);
        }
        __syncthreads();   // drains glds (vmcnt); buf cur reads complete
        cur ^= 1;
    }

    // ---- epilogue: invS from psum partials, scale, store ----
    const float* psb = psum + (size_t)b * NLC * NPAIR;
    #pragma unroll
    for (int m = 0; m < 4; ++m) {
        int lr0 = wr*64 + m*16 + kg*4;
        #pragma unroll
        for (int i = 0; i < 4; ++i) {
            int row = r0 + lr0 + i;
            if (row < NPAIR) {
                float S = psb[row] + psb[NPAIR + row];
                float sc = 1.f / (S + (float)NH * 1e-5f);
                #pragma unroll
                for (int n = 0; n < 2; ++n) {
                    int col = c0 + wc*32 + n*16 + fr;
                    fmap[((size_t)b*NPAIR + row)*DDIM + col] = acc[m][n][i] * sc;
                }
            }
        }
    }
#undef STAGE
}

// ---------------- launcher ---------------------------------------------------
extern "C" void kernel_launch(void* const* d_in, const int* in_sizes, int n_in,
                              void* d_out, int out_size, void* d_ws, size_t ws_size,
                              hipStream_t stream) {
    const float* seq  = (const float*)d_in[0];
    const float* att  = (const float*)d_in[1];
    const int*   mpos = (const int*)d_in[2];
    const int*   ment = (const int*)d_in[3];
    const int*   hts  = (const int*)d_in[4];

    float* ws_f  = (float*)d_ws;
    float* e_emb = ws_f;
    float* psum  = ws_f + EMB_CNT;
    __hip_bfloat16* e_att = (__hip_bfloat16*)(ws_f + EMB_CNT + PSUM_CNT);
    unsigned char* ptil = (unsigned char*)(e_att + EATT_CNT);
    unsigned char* seqT = ptil + PTIL_BYTES;

    float* out_h = (float*)d_out;
    float* out_t = out_h + (size_t)BSZ*NPAIR*DDIM;
    float* fmap  = out_t + (size_t)BSZ*NPAIR*DDIM;

    hipLaunchKernelGGL(prep_kernel, dim3(K1_TOTAL), dim3(256), 0, stream,
                       seq, att, mpos, ment, e_att, seqT, e_emb);
    hipLaunchKernelGGL(mid_kernel, dim3(K2_TOTAL), dim3(256), 0, stream,
                       e_att, e_emb, hts, ptil, psum, out_h, out_t);
    hipLaunchKernelGGL(gemm_kernel, dim3(FMAP_BLKS), dim3(256), 0, stream,
                       ptil, seqT, psum, fmap);
}

// Round 15
// 51.731 us; speedup vs baseline: 1.0994x; 1.0994x over previous
//
#include <hip/hip_runtime.h>
#include <hip/hip_bf16.h>

#define BSZ   4
#define LSEQ  1024
#define NH    12
#define DDIM  768
#define NEN   42
#define NM    96
#define NPAIR (NEN*NEN)   /* 1764 */
#define OFF   1

typedef short bf16x8 __attribute__((ext_vector_type(8)));
typedef float f32x4  __attribute__((ext_vector_type(4)));

__device__ __forceinline__ float bf2f(unsigned short u) {
    union { unsigned u; float f; } c; c.u = ((unsigned)u) << 16; return c.f;
}

typedef const __attribute__((address_space(1))) unsigned int glb_u32;
typedef __attribute__((address_space(3))) unsigned int lds_u32;
__device__ __forceinline__ void glds16(const void* g, void* l) {
    __builtin_amdgcn_global_load_lds((glb_u32*)g, (lds_u32*)l, 16, 0, 0);
}

// ---------------- workspace layout ----------------
// f32: e_emb | psum   then bf16: e_att   then fp8: ptil | seqT
#define NLC   2                                     /* l-chunks (LSEQ/LCHK) */
#define EMB_CNT  (BSZ*NEN*DDIM)
#define PSUM_CNT (BSZ*NLC*NPAIR)
#define EATT_CNT (BSZ*NEN*NH*LSEQ)
#define PTIL_BYTES ((size_t)BSZ*NPAIR*LSEQ)

// K1: ent_att only
#define ATT_TOTAL (BSZ*NEN*NH)                      /* 2016 */

// K2: pair tiles | seq transpose | ent_emb
#define TEN   6
#define NTILE 7                                     /* 42/6 */
#define NTRIT (NTILE*(NTILE+1)/2)                   /* 28 */
#define LCHK  512
#define PAIR_BLKS (NTRIT*NLC*BSZ)                   /* 224 */
#define T_BLKS    ((LSEQ/32)*(DDIM/32)*BSZ)         /* 3072 */
#define EMB_BLKS  (BSZ*NEN*3)                       /* 504 */
#define MID2_TOTAL (PAIR_BLKS + T_BLKS + EMB_BLKS)

// K3: fmap fp8 GEMM (XCD-swizzled) | gather
#define BM 128
#define BN 64
#define BK 128
#define MT 14           /* ceil(1764/128) */
#define NT (DDIM/BN)    /* 12 */
#define FMAP_BLKS (MT*NT*BSZ)                       /* 672, %8==0 */
#define GATH_BLKS (BSZ*NPAIR/4)                     /* 1764 */
#define TAIL_TOTAL (FMAP_BLKS + GATH_BLKS)

// ================= kernel 1: ent_att (segment mean -> bf16) ==================
__global__ __launch_bounds__(256) void att_kernel(
        const float* __restrict__ att,
        const int* __restrict__ mpos,
        const int* __restrict__ ment,
        __hip_bfloat16* __restrict__ e_att) {
    __shared__ int sp[NM];
    __shared__ int se[NM];
    __shared__ int list[NM];
    __shared__ int pcnt;
    int id = blockIdx.x;
    int h = id % NH;
    int e = (id / NH) % NEN;
    int b = id / (NH * NEN);
    int t = threadIdx.x;
    if (t < NM) { sp[t] = mpos[b*NM + t] + OFF; se[t] = ment[b*NM + t]; }
    __syncthreads();
    if (t == 0) {                        // deterministic compaction
        int c = 0;
        for (int m = 0; m < NM; ++m) if (se[m] == e) list[c++] = sp[m];
        pcnt = c;
    }
    __syncthreads();
    int cnt = pcnt;
    const float* ab = att + ((size_t)(b*NH + h)) * LSEQ * LSEQ;
    float4 acc = {0.f, 0.f, 0.f, 0.f};
    for (int m = 0; m < cnt; ++m) {
        float4 v = ((const float4*)(ab + (size_t)list[m]*LSEQ))[t];
        acc.x += v.x; acc.y += v.y; acc.z += v.z; acc.w += v.w;
    }
    float inv = cnt ? 1.f / (float)cnt : 0.f;
    union { ushort4 u4; __hip_bfloat16 hh[4]; } pk;
    pk.hh[0] = __float2bfloat16(acc.x * inv);
    pk.hh[1] = __float2bfloat16(acc.y * inv);
    pk.hh[2] = __float2bfloat16(acc.z * inv);
    pk.hh[3] = __float2bfloat16(acc.w * inv);
    ((ushort4*)(e_att + ((size_t)(b*NEN + e)*NH + h)*LSEQ))[t] = pk.u4;
}

// ================= kernel 2: pair tiles (+psum, fp8 out) | seqT fp8 | ent_emb
__global__ __launch_bounds__(256) void mid2_kernel(
        const float* __restrict__ seq,
        const __hip_bfloat16* __restrict__ e_att,
        const int* __restrict__ mpos,
        const int* __restrict__ ment,
        unsigned char* __restrict__ ptil,
        float* __restrict__ psum,
        unsigned char* __restrict__ seqT,
        float* __restrict__ e_emb) {
    __shared__ __align__(16) char smraw[4352];
    const int bid = blockIdx.x;
    const int t = threadIdx.x;

    if (bid < PAIR_BLKS) {
        // ---------- pair: 6x6 entity tile x 512-l chunk (2 l/thread) ---------
        int tri = bid % NTRIT;
        int lc  = (bid / NTRIT) % NLC;
        int b   = bid / (NTRIT * NLC);
        int ta = 0, rem = tri;
        while (rem >= NTILE - ta) { rem -= NTILE - ta; ++ta; }
        int tb = ta + rem;
        int l = lc * LCHK + t * 2;

        const __hip_bfloat16* ebase = e_att + (size_t)b*NEN*NH*LSEQ + l;
        float sx[TEN][TEN], sy[TEN][TEN];
        #pragma unroll
        for (int i = 0; i < TEN; ++i)
            #pragma unroll
            for (int j = 0; j < TEN; ++j) { sx[i][j] = 0.f; sy[i][j] = 0.f; }

        #pragma unroll 4
        for (int h = 0; h < NH; ++h) {
            float xax[TEN], xay[TEN], xbx[TEN], xby[TEN];
            #pragma unroll
            for (int e = 0; e < TEN; ++e) {
                ushort2 u = *(const ushort2*)(ebase + ((size_t)(ta*TEN+e)*NH + h)*LSEQ);
                xax[e] = bf2f(u.x); xay[e] = bf2f(u.y);
            }
            #pragma unroll
            for (int e = 0; e < TEN; ++e) {
                ushort2 u = *(const ushort2*)(ebase + ((size_t)(tb*TEN+e)*NH + h)*LSEQ);
                xbx[e] = bf2f(u.x); xby[e] = bf2f(u.y);
            }
            #pragma unroll
            for (int i = 0; i < TEN; ++i)
                #pragma unroll
                for (int j = 0; j < TEN; ++j) {
                    sx[i][j] += xax[i] * xbx[j];
                    sy[i][j] += xay[i] * xby[j];
                }
        }

        unsigned char* pbase = ptil + (size_t)b*NPAIR*LSEQ + l;
        #pragma unroll
        for (int i = 0; i < TEN; ++i) {
            #pragma unroll
            for (int j = 0; j < TEN; ++j) {
                int w = __builtin_amdgcn_cvt_pk_fp8_f32(sx[i][j], sy[i][j], 0, false);
                unsigned short q = (unsigned short)(w & 0xFFFF);
                int pa = ta*TEN + i, pb = tb*TEN + j;
                *(unsigned short*)(pbase + (size_t)(pa*NEN + pb)*LSEQ) = q;
                if (ta != tb)
                    *(unsigned short*)(pbase + (size_t)(pb*NEN + pa)*LSEQ) = q;
            }
        }

        // ---- deterministic partial row sums: wave shfl reduce + LDS combine
        int lane = t & 63, w = t >> 6;
        float (*redp)[TEN*TEN] = (float(*)[TEN*TEN])smraw;  // [4][36]
        float keep = 0.f;
        #pragma unroll
        for (int i = 0; i < TEN; ++i) {
            #pragma unroll
            for (int j = 0; j < TEN; ++j) {
                float v = sx[i][j] + sy[i][j];
                v += __shfl_xor(v,  1, 64);
                v += __shfl_xor(v,  2, 64);
                v += __shfl_xor(v,  4, 64);
                v += __shfl_xor(v,  8, 64);
                v += __shfl_xor(v, 16, 64);
                v += __shfl_xor(v, 32, 64);
                if (lane == i*TEN + j) keep = v;
            }
        }
        if (lane < TEN*TEN) redp[w][lane] = keep;
        __syncthreads();
        if (t < TEN*TEN) {
            float v = redp[0][t] + redp[1][t] + redp[2][t] + redp[3][t];
            int i = t / TEN, j = t % TEN;
            int pa = ta*TEN + i, pb = tb*TEN + j;
            float* ps = psum + ((size_t)(b*NLC + lc))*NPAIR;
            ps[pa*NEN + pb] = v;
            if (ta != tb) ps[pb*NEN + pa] = v;
        }
    } else if (bid < PAIR_BLKS + T_BLKS) {
        // ---------- seq2fp8T: seq f32 [L][D] -> seqT fp8 [D][L] --------------
        int id = bid - PAIR_BLKS;
        int l0 = (id % (LSEQ/32)) * 32;
        int d0 = ((id / (LSEQ/32)) % (DDIM/32)) * 32;
        int b  = id / ((LSEQ/32) * (DDIM/32));
        float (*tile)[33] = (float(*)[33])smraw;
        int l = t >> 3, dq = (t & 7) * 4;
        float4 v = *(const float4*)(seq + ((size_t)b*LSEQ + l0 + l)*DDIM + d0 + dq);
        tile[l][dq+0] = v.x; tile[l][dq+1] = v.y;
        tile[l][dq+2] = v.z; tile[l][dq+3] = v.w;
        __syncthreads();
        int d = t >> 3, lq = (t & 7) * 4;
        int w = __builtin_amdgcn_cvt_pk_fp8_f32(tile[lq+0][d], tile[lq+1][d], 0, false);
        w     = __builtin_amdgcn_cvt_pk_fp8_f32(tile[lq+2][d], tile[lq+3][d], w, true);
        *(int*)(seqT + ((size_t)b*DDIM + d0 + d)*LSEQ + l0 + lq) = w;
    } else {
        // ---------- ent_emb: segment logsumexp, one 256-d chunk per block ----
        int id = bid - PAIR_BLKS - T_BLKS;
        int chunk = id % 3;
        int e = (id / 3) % NEN;
        int b = id / (3 * NEN);
        int* sp   = (int*)smraw;
        int* se   = sp + NM;
        int* list = se + NM;
        int* pcnt = list + NM;
        if (t < NM) { sp[t] = mpos[b*NM + t] + OFF; se[t] = ment[b*NM + t]; }
        __syncthreads();
        if (t == 0) {
            int c = 0;
            for (int m = 0; m < NM; ++m) if (se[m] == e) list[c++] = sp[m];
            pcnt[0] = c;
        }
        __syncthreads();
        int cnt = pcnt[0];
        int d = chunk * 256 + t;
        const float* sq = seq + (size_t)b * LSEQ * DDIM + d;
        float mx = -1e30f;
        for (int m = 0; m < cnt; ++m) mx = fmaxf(mx, sq[(size_t)list[m] * DDIM]);
        float out = 0.f;
        if (cnt) {
            float s = 0.f;
            for (int m = 0; m < cnt; ++m) s += expf(sq[(size_t)list[m] * DDIM] - mx);
            out = logf(fmaxf(s, 1e-30f)) + mx;
        }
        e_emb[((size_t)b*NEN + e)*DDIM + d] = out;
    }
}

// ================= kernel 3: tail = fp8 fmap GEMM (counted vmcnt) | gather ===
// LDS rows are 128 B (fp8). Swizzle: 16B slot ^= (row&7)  (glds 16B-aligned)
__global__ __launch_bounds__(256) void tail_kernel(
        const unsigned char* __restrict__ ptil,
        const unsigned char* __restrict__ seqT,
        const float* __restrict__ psum,
        const float* __restrict__ e_emb,
        const int* __restrict__ hts,
        float* __restrict__ out_h,
        float* __restrict__ out_t,
        float* __restrict__ fmap) {
    __shared__ unsigned char As[2][BM*BK];      // 2 x 16 KB, swizzled linear
    __shared__ unsigned char Bs[2][BN*BK];      // 2 x  8 KB
    const int bid = blockIdx.x;
    const int t = threadIdx.x;

    if (bid >= FMAP_BLKS) {
        // ---------- gather hss / tss: 4 pairs per block ----------------------
        int id4  = bid - FMAP_BLKS;
        int grp  = t >> 6;
        int lane = t & 63;
        int id   = id4 * 4 + grp;                // b*NPAIR + p
        int b    = id / NPAIR;
        int hi = hts[id*2 + 0];
        int ti = hts[id*2 + 1];
        const float4* eh = (const float4*)(e_emb + ((size_t)(b*NEN + hi))*DDIM);
        const float4* et = (const float4*)(e_emb + ((size_t)(b*NEN + ti))*DDIM);
        float4* oh = (float4*)(out_h + (size_t)id*DDIM);
        float4* ot = (float4*)(out_t + (size_t)id*DDIM);
        #pragma unroll
        for (int i = 0; i < 3; ++i) {            // 192 float4 per row
            oh[lane + 64*i] = eh[lane + 64*i];
            ot[lane + 64*i] = et[lane + 64*i];
        }
        return;
    }

    // ---------- fmap GEMM (XCD-chunked tile mapping; 672 % 8 == 0) ----------
    int tile = (bid & 7) * (FMAP_BLKS/8) + (bid >> 3);
    const int lane = t & 63;
    const int wid  = t >> 6;
    const int wr   = wid >> 1;      // 0..1 : 64-row half
    const int wc   = wid & 1;       // 0..1 : 32-col half
    const int bx = tile % MT, by = (tile / MT) % NT, b = tile / (MT*NT);
    const int r0 = bx * BM, c0 = by * BN;

    const unsigned char* Ab  = ptil + (size_t)b * NPAIR * LSEQ;
    const unsigned char* Btb = seqT + (size_t)b * DDIM * LSEQ;
    unsigned char* AsB = (unsigned char*)As;
    unsigned char* BsB = (unsigned char*)Bs;

    const f32x4 zero = {0.f, 0.f, 0.f, 0.f};
    f32x4 acc[4][2];
    #pragma unroll
    for (int m = 0; m < 4; ++m)
        #pragma unroll
        for (int n = 0; n < 2; ++n) acc[m][n] = zero;

    const int fr = lane & 15, kg = lane >> 4;

#define STAGE(buf, k0)                                                        \
    {                                                                         \
        _Pragma("unroll")                                                     \
        for (int i = 0; i < 4; ++i) {                                         \
            int L = t*16 + i*4096;                                            \
            int r = L >> 7, beta = L & 127;                                   \
            glds16(Ab + (size_t)(r0 + r)*LSEQ + (k0)                          \
                      + (beta ^ ((r & 7) << 4)),                              \
                   AsB + (buf)*16384 + L);                                    \
        }                                                                     \
        _Pragma("unroll")                                                     \
        for (int i = 0; i < 2; ++i) {                                         \
            int L = t*16 + i*4096;                                            \
            int c = L >> 7, beta = L & 127;                                   \
            glds16(Btb + (size_t)(c0 + c)*LSEQ + (k0)                         \
                      + (beta ^ ((c & 7) << 4)),                              \
                   BsB + (buf)*8192 + L);                                     \
        }                                                                     \
    }

    STAGE(0, 0);     // 6 glds in flight for buf 0

    int cur = 0;
    for (int ki = 0; ki < LSEQ/BK; ++ki) {
        // issue next tile, then wait ONLY for cur's 6 loads (counted vmcnt —
        // next's 6 stay in flight across both barriers; T4 pattern)
        if (ki + 1 < LSEQ/BK) {
            STAGE(cur ^ 1, (ki + 1) * BK);
            asm volatile("s_waitcnt vmcnt(6)" ::: "memory");
        } else {
            asm volatile("s_waitcnt vmcnt(0)" ::: "memory");
        }
        __builtin_amdgcn_s_barrier();          // all waves' cur loads landed
        __builtin_amdgcn_sched_barrier(0);     // rule #18: no hoist above wait

        const unsigned char* Ac = AsB + cur*16384;
        const unsigned char* Bc = BsB + cur*8192;

        #pragma unroll
        for (int ks = 0; ks < 4; ++ks) {
            long af[4], bfv[2];
            #pragma unroll
            for (int m = 0; m < 4; ++m) {
                int R = wr*64 + m*16 + fr;
                int e0 = (ks*32 + kg*8) ^ ((R & 7) << 4);
                af[m] = *(const long*)(Ac + R*128 + e0);
            }
            #pragma unroll
            for (int n = 0; n < 2; ++n) {
                int C = wc*32 + n*16 + fr;
                int e0 = (ks*32 + kg*8) ^ ((C & 7) << 4);
                bfv[n] = *(const long*)(Bc + C*128 + e0);
            }
            #pragma unroll
            for (int m = 0; m < 4; ++m)
                #pragma unroll
                for (int n = 0; n < 2; ++n)
                    acc[m][n] = __builtin_amdgcn_mfma_f32_16x16x32_fp8_fp8(
                                    af[m], bfv[n], acc[m][n], 0, 0, 0);
        }
        __builtin_amdgcn_s_barrier();          // reads of buf cur complete
        cur ^= 1;
    }

    // ---- epilogue: invS from psum partials, scale, store ----
    const float* psb = psum + (size_t)b * NLC * NPAIR;
    #pragma unroll
    for (int m = 0; m < 4; ++m) {
        int lr0 = wr*64 + m*16 + kg*4;
        #pragma unroll
        for (int i = 0; i < 4; ++i) {
            int row = r0 + lr0 + i;
            if (row < NPAIR) {
                float S = psb[row] + psb[NPAIR + row];
                float sc = 1.f / (S + (float)NH * 1e-5f);
                #pragma unroll
                for (int n = 0; n < 2; ++n) {
                    int col = c0 + wc*32 + n*16 + fr;
                    fmap[((size_t)b*NPAIR + row)*DDIM + col] = acc[m][n][i] * sc;
                }
            }
        }
    }
#undef STAGE
}

// ---------------- launcher ---------------------------------------------------
extern "C" void kernel_launch(void* const* d_in, const int* in_sizes, int n_in,
                              void* d_out, int out_size, void* d_ws, size_t ws_size,
                              hipStream_t stream) {
    const float* seq  = (const float*)d_in[0];
    const float* att  = (const float*)d_in[1];
    const int*   mpos = (const int*)d_in[2];
    const int*   ment = (const int*)d_in[3];
    const int*   hts  = (const int*)d_in[4];

    float* ws_f  = (float*)d_ws;
    float* e_emb = ws_f;
    float* psum  = ws_f + EMB_CNT;
    __hip_bfloat16* e_att = (__hip_bfloat16*)(ws_f + EMB_CNT + PSUM_CNT);
    unsigned char* ptil = (unsigned char*)(e_att + EATT_CNT);
    unsigned char* seqT = ptil + PTIL_BYTES;

    float* out_h = (float*)d_out;
    float* out_t = out_h + (size_t)BSZ*NPAIR*DDIM;
    float* fmap  = out_t + (size_t)BSZ*NPAIR*DDIM;

    hipLaunchKernelGGL(att_kernel, dim3(ATT_TOTAL), dim3(256), 0, stream,
                       att, mpos, ment, e_att);
    hipLaunchKernelGGL(mid2_kernel, dim3(MID2_TOTAL), dim3(256), 0, stream,
                       seq, e_att, mpos, ment, ptil, psum, seqT, e_emb);
    hipLaunchKernelGGL(tail_kernel, dim3(TAIL_TOTAL), dim3(256), 0, stream,
                       ptil, seqT, psum, e_emb, hts, out_h, out_t, fmap);
}